// Round 4
// baseline (22.733 us; speedup 1.0000x reference)
//
#include <hip/hip_runtime.h>
#include <math.h>

constexpr int kB = 2, kP = 300, kF = 512, kH = 128, kW = 128, kTH = 512, kTW = 512;
constexpr float kDelta = 7000.0f;
constexpr float kCut = 0.06f;              // band cutoff: p < 1.2e-11 beyond -> skip
constexpr float kThr = 0.1374f;            // kCut + tile-center->pixel-center radius (0.07734)
constexpr float kLogInside = -15.9423847f; // log1p(-(1-1e-7f)) = ln(2^-23)

// One fused kernel. Grid: 512 blocks = 2 batches x 256 tiles (8x8 px).
// Block: 512 threads = 8 waves; wave wv owns compacted slots [wv*64, wv*64+64).
// Record (12 floats): h0=(A0,B0,C0,A1) h1=(B1,C1,A2,B2) h2=(C2,az,bz,cz)
//   where L_i(p) = A_i px + B_i py + C_i = SIGNED DISTANCE to edge-line i
//   (edge functions scaled by h_i = area/len_i > 0; sign(L_i) == sign(w_i)).
__global__ __launch_bounds__(512, 8) void render_all(const float* __restrict__ pts,
                                                     const int* __restrict__ faces,
                                                     const float* __restrict__ uvs,
                                                     const float* __restrict__ tex,
                                                     float* __restrict__ out) {
    __shared__ float4 s_hot4[kF * 3];      // 24 KB
    __shared__ unsigned short s_of[kF];    // 1 KB: slot -> original face
    __shared__ int s_wsum[8];
    __shared__ float s_bz[512];
    __shared__ int s_bi[512];
    __shared__ float s_lm[512];

    int tile = (int)blockIdx.x;
    int b = tile >> 8;
    int rem = tile & 255;
    int ty = rem >> 4, tx = rem & 15;
    int tid = (int)threadIdx.x;
    int lane = tid & 63;
    int wv = tid >> 6;

    // ---------- setup: thread tid processes face tid for batch b ----------
    {
        int f = tid;
        int i0 = faces[f * 3 + 0], i1 = faces[f * 3 + 1], i2 = faces[f * 3 + 2];
        const float* pb = pts + b * kP * 3;
        float x0 = pb[i0 * 3], y0 = pb[i0 * 3 + 1], z0 = pb[i0 * 3 + 2];
        float x1 = pb[i1 * 3], y1 = pb[i1 * 3 + 1], z1 = pb[i1 * 3 + 2];
        float x2 = pb[i2 * 3], y2 = pb[i2 * 3 + 1], z2 = pb[i2 * 3 + 2];
        float area = (x1 - x0) * (y2 - y0) - (y1 - y0) * (x2 - x0);
        bool front = area > 1e-8f;

        // pre-fill row h0 so empty slots are ballot-culled (L0 = -1e30)
        s_hot4[f * 3 + 0] = make_float4(0.0f, 0.0f, -1e30f, 0.0f);
        unsigned long long bal = __ballot(front);
        if (lane == 0) s_wsum[wv] = __popcll(bal);
        __syncthreads();  // wsum + pre-fill visible

        int base = 0;
#pragma unroll
        for (int w = 0; w < 8; ++w) base += (w < wv) ? s_wsum[w] : 0;
        int slot = base + __popcll(bal & ((1ull << lane) - 1ull));

        if (front) {
            float inv_a = 1.0f / area;
            float e0x = x2 - x1, e0y = y2 - y1;
            float e1x = x0 - x2, e1y = y0 - y2;
            float e2x = x1 - x0, e2y = y1 - y0;
            float l0 = fmaf(e0x, e0x, e0y * e0y);
            float l1 = fmaf(e1x, e1x, e1y * e1y);
            float l2 = fmaf(e2x, e2x, e2y * e2y);
            float h0s = area * rsqrtf(l0 + 1e-12f);  // = area/len0
            float h1s = area * rsqrtf(l1 + 1e-12f);
            float h2s = area * rsqrtf(l2 + 1e-12f);
            // w_i coefficients (reference _edge * inv_a), then scale by h_i
            float s0 = inv_a * h0s, s1 = inv_a * h1s, s2 = inv_a * h2s;
            float A0 = -e0y * s0, B0 = e0x * s0, C0 = (e0y * x1 - e0x * y1) * s0;
            float A1 = -e1y * s1, B1 = e1x * s1, C1 = (e1y * x2 - e1x * y2) * s1;
            float A2 = -e2y * s2, B2 = e2x * s2, C2 = (e2y * x0 - e2x * y0) * s2;
            float a0 = -e0y * inv_a, b0 = e0x * inv_a, c0 = (e0y * x1 - e0x * y1) * inv_a;
            float a1 = -e1y * inv_a, b1 = e1x * inv_a, c1 = (e1y * x2 - e1x * y2) * inv_a;
            float a2 = -e2y * inv_a, b2 = e2x * inv_a, c2 = (e2y * x0 - e2x * y0) * inv_a;
            s_hot4[slot * 3 + 0] = make_float4(A0, B0, C0, A1);
            s_hot4[slot * 3 + 1] = make_float4(B1, C1, A2, B2);
            s_hot4[slot * 3 + 2] = make_float4(C2,
                                               a0 * z0 + a1 * z1 + a2 * z2,
                                               b0 * z0 + b1 * z1 + b2 * z2,
                                               c0 * z0 + c1 * z1 + c2 * z2);
            s_of[slot] = (unsigned short)f;
        }
    }
    __syncthreads();

    // ---------- render ----------
    int pyi = ty * 8 + (lane >> 3);
    int pxi = tx * 8 + (lane & 7);
    float px = ((float)pxi + 0.5f) * (2.0f / 128.0f) - 1.0f;
    float py = 1.0f - ((float)pyi + 0.5f) * (2.0f / 128.0f);

    // ballot cull: lane l tests slot wv*64+l against tile center half-planes
    {
    }
    float cx = (float)(tx * 8 + 4) * (2.0f / 128.0f) - 1.0f;
    float cy = 1.0f - (float)(ty * 8 + 4) * (2.0f / 128.0f);
    int slt = (wv << 6) + lane;
    float4 g0 = s_hot4[slt * 3 + 0];
    float4 g1 = s_hot4[slt * 3 + 1];
    float4 g2 = s_hot4[slt * 3 + 2];
    float Lc0 = fmaf(g0.x, cx, fmaf(g0.y, cy, g0.z));
    float Lc1 = fmaf(g0.w, cx, fmaf(g1.x, cy, g1.y));
    float Lc2 = fmaf(g1.z, cx, fmaf(g1.w, cy, g2.x));
    float minc = fminf(fminf(Lc0, Lc1), Lc2);  // fminf drops NaN garbage; empty -> -1e30
    unsigned long long m = __ballot(minc >= -kThr);

    float bestz = -1e9f;
    int besti = -1, icnt = 0;
    float lm = 0.0f;
    const float* pb = pts + b * kP * 3;

    while (m) {
        int l = (int)__builtin_ctzll(m);
        m &= (m - 1);
        int fs = (wv << 6) + l;  // wave-uniform, ascending
        float4 h0 = s_hot4[fs * 3 + 0];
        float4 h1 = s_hot4[fs * 3 + 1];
        float4 h2 = s_hot4[fs * 3 + 2];
        float L0 = fmaf(h0.x, px, fmaf(h0.y, py, h0.z));
        float L1 = fmaf(h0.w, px, fmaf(h1.x, py, h1.y));
        float L2 = fmaf(h1.z, px, fmaf(h1.w, py, h2.x));
        float minL = fminf(fminf(L0, L1), L2);
        bool inside = minL >= 0.0f;
        float z = fmaf(h2.y, px, fmaf(h2.z, py, h2.w));
        if (inside && z > bestz) { bestz = z; besti = fs; }
        icnt += inside ? 1 : 0;
        float db = fminf(fminf(fabsf(L0), fabsf(L1)), fabsf(L2));  // >= dist lower bound
        bool need = (!inside) & (db < kCut);
        if (__any(need)) {
            int of = __builtin_amdgcn_readfirstlane((int)s_of[fs]);
            int j0 = faces[of * 3], j1 = faces[of * 3 + 1], j2 = faces[of * 3 + 2];
            float x0 = pb[j0 * 3], y0 = pb[j0 * 3 + 1];
            float x1 = pb[j1 * 3], y1 = pb[j1 * 3 + 1];
            float x2 = pb[j2 * 3], y2 = pb[j2 * 3 + 1];
            // seg dist^2: |L_i| is exact line distance; use it when the
            // projection lies within the segment, else vertex distances.
            float e0x = x2 - x1, e0y = y2 - y1;   // seg v1->v2  (line 0)
            float e1x = x0 - x2, e1y = y0 - y2;   // seg v2->v0  (line 1)
            float e2x = x1 - x0, e2y = y1 - y0;   // seg v0->v1  (line 2)
            float p0x = px - x0, p0y = py - y0;
            float p1x = px - x1, p1y = py - y1;
            float p2x = px - x2, p2y = py - y2;
            float dot0 = fmaf(p1x, e0x, p1y * e0y), len0 = fmaf(e0x, e0x, e0y * e0y);
            float dot1 = fmaf(p2x, e1x, p2y * e1y), len1 = fmaf(e1x, e1x, e1y * e1y);
            float dot2 = fmaf(p0x, e2x, p0y * e2y), len2 = fmaf(e2x, e2x, e2y * e2y);
            float c0 = (dot0 >= 0.0f && dot0 <= len0) ? L0 * L0 : 1e30f;
            float c1 = (dot1 >= 0.0f && dot1 <= len1) ? L1 * L1 : 1e30f;
            float c2 = (dot2 >= 0.0f && dot2 <= len2) ? L2 * L2 : 1e30f;
            float dv0 = fmaf(p0x, p0x, p0y * p0y);
            float dv1 = fmaf(p1x, p1x, p1y * p1y);
            float dv2 = fmaf(p2x, p2x, p2y * p2y);
            float d2 = fminf(fminf(fminf(c0, c1), fminf(c2, dv0)), fminf(dv1, dv2));
            float p = __expf(-kDelta * d2);
            p = fminf(p, 1.0f - 1e-7f);
            float lp = __logf(1.0f - p);  // == log1p(-p): 1-p exact for p >= 0.5
            lm += need ? lp : 0.0f;
        }
    }
    lm = fmaf((float)icnt, kLogInside, lm);

    s_bz[tid] = bestz;
    s_bi[tid] = besti;
    s_lm[tid] = lm;
    __syncthreads();

    if (tid < 64) {
        float bz = s_bz[tid];
        int bi = s_bi[tid];
        float L = s_lm[tid];
#pragma unroll
        for (int w = 1; w < 8; ++w) {
            float z2 = s_bz[w * 64 + tid];
            int ii = s_bi[w * 64 + tid];
            L += s_lm[w * 64 + tid];
            // first-max semantics: lower slot (== earlier original face) wins ties
            if (z2 > bz || (z2 == bz && ii >= 0 && (unsigned)ii < (unsigned)bi)) {
                bz = z2; bi = ii;
            }
        }
        float improb = 1.0f - expf(L);
        float u = 0.0f, v = 0.0f, mk = 0.0f;
        if (bi >= 0) {
            int of = (int)s_of[bi];
            int j0 = faces[of * 3], j1 = faces[of * 3 + 1], j2 = faces[of * 3 + 2];
            float x0 = pb[j0 * 3], y0 = pb[j0 * 3 + 1];
            float x1 = pb[j1 * 3], y1 = pb[j1 * 3 + 1];
            float x2 = pb[j2 * 3], y2 = pb[j2 * 3 + 1];
            float area = (x1 - x0) * (y2 - y0) - (y1 - y0) * (x2 - x0);
            float inv_a = 1.0f / area;
            // exact reference formulation
            float w0 = ((x2 - x1) * (py - y1) - (y2 - y1) * (px - x1)) * inv_a;
            float w1 = ((x0 - x2) * (py - y2) - (y0 - y2) * (px - x2)) * inv_a;
            float w2 = ((x1 - x0) * (py - y0) - (y1 - y0) * (px - x0)) * inv_a;
            const float* ub = uvs + b * kP * 2;
            u = w0 * ub[j0 * 2] + w1 * ub[j1 * 2] + w2 * ub[j2 * 2];
            v = w0 * ub[j0 * 2 + 1] + w1 * ub[j1 * 2 + 1] + w2 * ub[j2 * 2 + 1];
            mk = w0 + w1 + w2;
        }
        float uc = fminf(fmaxf(u, 0.0f), 1.0f);
        float vc = fminf(fmaxf(v, 0.0f), 1.0f);
        float fx = uc * (float)(kTW - 1);
        float fy = (1.0f - vc) * (float)(kTH - 1);
        int xi0 = (int)floorf(fx), yi0 = (int)floorf(fy);
        int xi1 = min(xi0 + 1, kTW - 1), yi1 = min(yi0 + 1, kTH - 1);
        float wx = fx - (float)xi0, wy = fy - (float)yi0;
        float w00 = (1.0f - wx) * (1.0f - wy);
        float w01 = wx * (1.0f - wy);
        float w10 = (1.0f - wx) * wy;
        float w11 = wx * wy;
        int o00 = yi0 * kTW + xi0, o01 = yi0 * kTW + xi1;
        int o10 = yi1 * kTW + xi0, o11 = yi1 * kTW + xi1;
        const float* tb = tex + (size_t)b * 3 * kTH * kTW;
        float cols[3];
#pragma unroll
        for (int c = 0; c < 3; ++c) {
            const float* tc = tb + c * kTH * kTW;
            cols[c] = (tc[o00] * w00 + tc[o01] * w01 + tc[o10] * w10 + tc[o11] * w11) * mk;
        }
        int pix = (b * kH + pyi) * kW + pxi;
        out[pix * 3 + 0] = cols[0];
        out[pix * 3 + 1] = cols[1];
        out[pix * 3 + 2] = cols[2];
        out[kB * kH * kW * 3 + pix] = improb;
    }
}

extern "C" void kernel_launch(void* const* d_in, const int* in_sizes, int n_in,
                              void* d_out, int out_size, void* d_ws, size_t ws_size,
                              hipStream_t stream) {
    const float* pts = (const float*)d_in[0];
    const int* faces = (const int*)d_in[1];
    const float* uvs = (const float*)d_in[2];
    const float* tex = (const float*)d_in[3];
    float* out = (float*)d_out;
    render_all<<<kB * 256, 512, 0, stream>>>(pts, faces, uvs, tex, out);
}

// Round 5
// 20.381 us; speedup vs baseline: 1.1154x; 1.1154x over previous
//
#include <hip/hip_runtime.h>
#include <math.h>

constexpr int kB = 2, kP = 300, kF = 512, kH = 128, kW = 128, kTH = 512, kTW = 512;
constexpr float kDelta = 7000.0f;
constexpr float kCut = 0.06f;              // band cutoff: p < 1.2e-11 beyond -> skip
constexpr float kThr = 0.1374f;            // kCut + tile-center->pixel-center radius
constexpr float kLogInside = -15.9423847f; // log1p(-(1-1e-7f)) = ln(2^-23)

// One fused kernel. Grid: 512 blocks = 2 batches x 256 tiles (8x8 px).
// Block: 512 threads = 8 waves; wave wv owns compacted slots [wv*64, wv*64+64).
// Hot record (12 floats): h0=(A0,B0,C0,A1) h1=(B1,C1,A2,B2) h2=(C2,az,bz,cz)
//   L_i(p) = A_i px + B_i py + C_i = SIGNED DISTANCE to edge-line i (unit normal;
//   sign(L_i) == sign(w_i) since h_i = area/len_i > 0).
__global__ __launch_bounds__(512, 6) void render_all(const float* __restrict__ pts,
                                                     const int* __restrict__ faces,
                                                     const float* __restrict__ uvs,
                                                     const float* __restrict__ tex,
                                                     float* __restrict__ out) {
    __shared__ float4 s_hot4[kF * 3];      // 24 KB
    __shared__ float2 s_vtx[kF * 3];       // 12 KB: (x0,y0),(x1,y1),(x2,y2)
    __shared__ unsigned short s_of[kF];    // 1 KB: slot -> original face
    __shared__ int s_wsum[8];
    __shared__ float s_bz[512];
    __shared__ int s_bi[512];
    __shared__ float s_lm[512];

    int tile = (int)blockIdx.x;
    int b = tile >> 8;
    int rem = tile & 255;
    int ty = rem >> 4, tx = rem & 15;
    int tid = (int)threadIdx.x;
    int lane = tid & 63;
    int wv = tid >> 6;

    // ---------- setup: thread tid processes face tid for batch b ----------
    {
        int f = tid;
        int i0 = faces[f * 3 + 0], i1 = faces[f * 3 + 1], i2 = faces[f * 3 + 2];
        const float* pb = pts + b * kP * 3;
        float x0 = pb[i0 * 3], y0 = pb[i0 * 3 + 1], z0 = pb[i0 * 3 + 2];
        float x1 = pb[i1 * 3], y1 = pb[i1 * 3 + 1], z1 = pb[i1 * 3 + 2];
        float x2 = pb[i2 * 3], y2 = pb[i2 * 3 + 1], z2 = pb[i2 * 3 + 2];
        float area = (x1 - x0) * (y2 - y0) - (y1 - y0) * (x2 - x0);
        bool front = area > 1e-8f;

        // pre-fill row h0 so empty tail slots are ballot-culled (L0 = -1e30)
        s_hot4[f * 3 + 0] = make_float4(0.0f, 0.0f, -1e30f, 0.0f);
        unsigned long long bal = __ballot(front);
        if (lane == 0) s_wsum[wv] = __popcll(bal);
        __syncthreads();  // wsum + pre-fill visible

        int base = 0;
#pragma unroll
        for (int w = 0; w < 8; ++w) base += (w < wv) ? s_wsum[w] : 0;
        int slot = base + __popcll(bal & ((1ull << lane) - 1ull));

        if (front) {
            float inv_a = 1.0f / area;
            float e0x = x2 - x1, e0y = y2 - y1;
            float e1x = x0 - x2, e1y = y0 - y2;
            float e2x = x1 - x0, e2y = y1 - y0;
            float l0 = fmaf(e0x, e0x, e0y * e0y);
            float l1 = fmaf(e1x, e1x, e1y * e1y);
            float l2 = fmaf(e2x, e2x, e2y * e2y);
            float s0 = rsqrtf(l0 + 1e-12f);  // 1/len0  (unit-normal scale)
            float s1 = rsqrtf(l1 + 1e-12f);
            float s2 = rsqrtf(l2 + 1e-12f);
            float A0 = -e0y * s0, B0 = e0x * s0, C0 = (e0y * x1 - e0x * y1) * s0;
            float A1 = -e1y * s1, B1 = e1x * s1, C1 = (e1y * x2 - e1x * y2) * s1;
            float A2 = -e2y * s2, B2 = e2x * s2, C2 = (e2y * x0 - e2x * y0) * s2;
            float a0 = -e0y * inv_a, b0 = e0x * inv_a, c0 = (e0y * x1 - e0x * y1) * inv_a;
            float a1 = -e1y * inv_a, b1 = e1x * inv_a, c1 = (e1y * x2 - e1x * y2) * inv_a;
            float a2 = -e2y * inv_a, b2 = e2x * inv_a, c2 = (e2y * x0 - e2x * y0) * inv_a;
            s_hot4[slot * 3 + 0] = make_float4(A0, B0, C0, A1);
            s_hot4[slot * 3 + 1] = make_float4(B1, C1, A2, B2);
            s_hot4[slot * 3 + 2] = make_float4(C2,
                                               a0 * z0 + a1 * z1 + a2 * z2,
                                               b0 * z0 + b1 * z1 + b2 * z2,
                                               c0 * z0 + c1 * z1 + c2 * z2);
            s_vtx[slot * 3 + 0] = make_float2(x0, y0);
            s_vtx[slot * 3 + 1] = make_float2(x1, y1);
            s_vtx[slot * 3 + 2] = make_float2(x2, y2);
            s_of[slot] = (unsigned short)f;
        }
    }
    __syncthreads();

    // ---------- render ----------
    int pyi = ty * 8 + (lane >> 3);
    int pxi = tx * 8 + (lane & 7);
    float px = ((float)pxi + 0.5f) * (2.0f / 128.0f) - 1.0f;
    float py = 1.0f - ((float)pyi + 0.5f) * (2.0f / 128.0f);

    // ballot cull: lane l tests slot wv*64+l half-planes at the tile center.
    // Conservative: L_i has unit gradient, so a contributing pixel implies
    // L_i(center) >= -(kCut + tile_radius) for all i.
    float cx = (float)(tx * 8 + 4) * (2.0f / 128.0f) - 1.0f;
    float cy = 1.0f - (float)(ty * 8 + 4) * (2.0f / 128.0f);
    int slt = (wv << 6) + lane;
    float4 g0 = s_hot4[slt * 3 + 0];
    float4 g1 = s_hot4[slt * 3 + 1];
    float4 g2 = s_hot4[slt * 3 + 2];
    float Lc0 = fmaf(g0.x, cx, fmaf(g0.y, cy, g0.z));
    float Lc1 = fmaf(g0.w, cx, fmaf(g1.x, cy, g1.y));
    float Lc2 = fmaf(g1.z, cx, fmaf(g1.w, cy, g2.x));
    float minc = fminf(fminf(Lc0, Lc1), Lc2);  // fminf drops NaN garbage; empty -> -1e30
    unsigned long long m = __ballot(minc >= -kThr);

    float bestz = -1e9f;
    int besti = -1, icnt = 0;
    float lm = 0.0f;

    while (m) {
        int l = (int)__builtin_ctzll(m);
        m &= (m - 1);
        int fs = (wv << 6) + l;  // wave-uniform, ascending
        float4 h0 = s_hot4[fs * 3 + 0];
        float4 h1 = s_hot4[fs * 3 + 1];
        float4 h2 = s_hot4[fs * 3 + 2];
        float L0 = fmaf(h0.x, px, fmaf(h0.y, py, h0.z));
        float L1 = fmaf(h0.w, px, fmaf(h1.x, py, h1.y));
        float L2 = fmaf(h1.z, px, fmaf(h1.w, py, h2.x));
        float minL = fminf(fminf(L0, L1), L2);
        bool inside = minL >= 0.0f;
        float z = fmaf(h2.y, px, fmaf(h2.z, py, h2.w));
        if (inside && z > bestz) { bestz = z; besti = fs; }
        icnt += inside ? 1 : 0;
        float db = fminf(fminf(fabsf(L0), fabsf(L1)), fabsf(L2));
        bool need = (!inside) & (db < kCut);
        if (__any(need)) {
            float2 v0 = s_vtx[fs * 3 + 0];
            float2 v1 = s_vtx[fs * 3 + 1];
            float2 v2 = s_vtx[fs * 3 + 2];
            float e0x = v2.x - v1.x, e0y = v2.y - v1.y;  // seg v1->v2 (line 0)
            float e1x = v0.x - v2.x, e1y = v0.y - v2.y;  // seg v2->v0 (line 1)
            float e2x = v1.x - v0.x, e2y = v1.y - v0.y;  // seg v0->v1 (line 2)
            float p0x = px - v0.x, p0y = py - v0.y;
            float p1x = px - v1.x, p1y = py - v1.y;
            float p2x = px - v2.x, p2y = py - v2.y;
            float dot0 = fmaf(p1x, e0x, p1y * e0y), len0 = fmaf(e0x, e0x, e0y * e0y);
            float dot1 = fmaf(p2x, e1x, p2y * e1y), len1 = fmaf(e1x, e1x, e1y * e1y);
            float dot2 = fmaf(p0x, e2x, p0y * e2y), len2 = fmaf(e2x, e2x, e2y * e2y);
            // |L_i| is the exact line distance; valid when projection in-range
            float c0 = (dot0 >= 0.0f && dot0 <= len0) ? L0 * L0 : 1e30f;
            float c1 = (dot1 >= 0.0f && dot1 <= len1) ? L1 * L1 : 1e30f;
            float c2 = (dot2 >= 0.0f && dot2 <= len2) ? L2 * L2 : 1e30f;
            float dv0 = fmaf(p0x, p0x, p0y * p0y);
            float dv1 = fmaf(p1x, p1x, p1y * p1y);
            float dv2 = fmaf(p2x, p2x, p2y * p2y);
            float d2 = fminf(fminf(fminf(c0, c1), fminf(c2, dv0)), fminf(dv1, dv2));
            float p = __expf(-kDelta * d2);
            p = fminf(p, 1.0f - 1e-7f);
            float lp = __logf(1.0f - p);  // == log1p(-p): 1-p exact for p >= 0.5
            lm += need ? lp : 0.0f;
        }
    }
    lm = fmaf((float)icnt, kLogInside, lm);

    s_bz[tid] = bestz;
    s_bi[tid] = besti;
    s_lm[tid] = lm;
    __syncthreads();

    if (tid < 64) {
        float bz = s_bz[tid];
        int bi = s_bi[tid];
        float L = s_lm[tid];
#pragma unroll
        for (int w = 1; w < 8; ++w) {
            float z2 = s_bz[w * 64 + tid];
            int ii = s_bi[w * 64 + tid];
            L += s_lm[w * 64 + tid];
            // first-max semantics: lower slot (== earlier original face) wins ties
            if (z2 > bz || (z2 == bz && ii >= 0 && (unsigned)ii < (unsigned)bi)) {
                bz = z2; bi = ii;
            }
        }
        float improb = 1.0f - expf(L);
        float u = 0.0f, v = 0.0f, mk = 0.0f;
        if (bi >= 0) {
            float2 v0 = s_vtx[bi * 3 + 0];
            float2 v1 = s_vtx[bi * 3 + 1];
            float2 v2 = s_vtx[bi * 3 + 2];
            float area = (v1.x - v0.x) * (v2.y - v0.y) - (v1.y - v0.y) * (v2.x - v0.x);
            float inv_a = 1.0f / area;
            // exact reference formulation
            float w0 = ((v2.x - v1.x) * (py - v1.y) - (v2.y - v1.y) * (px - v1.x)) * inv_a;
            float w1 = ((v0.x - v2.x) * (py - v2.y) - (v0.y - v2.y) * (px - v2.x)) * inv_a;
            float w2 = ((v1.x - v0.x) * (py - v0.y) - (v1.y - v0.y) * (px - v0.x)) * inv_a;
            int of = (int)s_of[bi];
            int j0 = faces[of * 3], j1 = faces[of * 3 + 1], j2 = faces[of * 3 + 2];
            const float* ub = uvs + b * kP * 2;
            u = w0 * ub[j0 * 2] + w1 * ub[j1 * 2] + w2 * ub[j2 * 2];
            v = w0 * ub[j0 * 2 + 1] + w1 * ub[j1 * 2 + 1] + w2 * ub[j2 * 2 + 1];
            mk = w0 + w1 + w2;
        }
        float uc = fminf(fmaxf(u, 0.0f), 1.0f);
        float vc = fminf(fmaxf(v, 0.0f), 1.0f);
        float fx = uc * (float)(kTW - 1);
        float fy = (1.0f - vc) * (float)(kTH - 1);
        int xi0 = (int)floorf(fx), yi0 = (int)floorf(fy);
        int xi1 = min(xi0 + 1, kTW - 1), yi1 = min(yi0 + 1, kTH - 1);
        float wx = fx - (float)xi0, wy = fy - (float)yi0;
        float w00 = (1.0f - wx) * (1.0f - wy);
        float w01 = wx * (1.0f - wy);
        float w10 = (1.0f - wx) * wy;
        float w11 = wx * wy;
        int o00 = yi0 * kTW + xi0, o01 = yi0 * kTW + xi1;
        int o10 = yi1 * kTW + xi0, o11 = yi1 * kTW + xi1;
        const float* tb = tex + (size_t)b * 3 * kTH * kTW;
        float cols[3];
#pragma unroll
        for (int c = 0; c < 3; ++c) {
            const float* tc = tb + c * kTH * kTW;
            cols[c] = (tc[o00] * w00 + tc[o01] * w01 + tc[o10] * w10 + tc[o11] * w11) * mk;
        }
        int pix = (b * kH + pyi) * kW + pxi;
        out[pix * 3 + 0] = cols[0];
        out[pix * 3 + 1] = cols[1];
        out[pix * 3 + 2] = cols[2];
        out[kB * kH * kW * 3 + pix] = improb;
    }
}

extern "C" void kernel_launch(void* const* d_in, const int* in_sizes, int n_in,
                              void* d_out, int out_size, void* d_ws, size_t ws_size,
                              hipStream_t stream) {
    const float* pts = (const float*)d_in[0];
    const int* faces = (const int*)d_in[1];
    const float* uvs = (const float*)d_in[2];
    const float* tex = (const float*)d_in[3];
    float* out = (float*)d_out;
    render_all<<<kB * 256, 512, 0, stream>>>(pts, faces, uvs, tex, out);
}

// Round 6
// 18.324 us; speedup vs baseline: 1.2406x; 1.1123x over previous
//
#include <hip/hip_runtime.h>
#include <math.h>

constexpr int kB = 2, kP = 300, kF = 512, kH = 128, kW = 128, kTH = 512, kTW = 512;
constexpr float kDelta = 7000.0f;
constexpr float kCut = 0.06f;              // band cutoff: p < 1.2e-11 beyond -> skip
constexpr float kThr2 = 0.018882f;         // (kCut + 0.0774 tile radius)^2
constexpr float kLogInside = -15.9423847f; // log1p(-(1-1e-7f)) = ln(2^-23)

// One fused kernel. Grid: 512 blocks = 2 batches x 256 tiles (8x8 px).
// Block: 512 threads = 8 waves. Compacted front-face k is DEALT to slot
// (k&7)*64 + (k>>3): wave wv owns contiguous slots [wv*64,wv*64+64) holding
// faces k === wv (mod 8)  -> balanced waves + lane-contiguous cull reads.
// Hot rows: sA=(A0,B0,C0,A1) sB=(B1,C1,A2,B2) sC=(C2,az,bz,cz);
// L_i(p) = A_i px + B_i py + C_i = signed distance to edge-line i (unit normal).
__global__ __launch_bounds__(512, 6) void render_all(const float* __restrict__ pts,
                                                     const int* __restrict__ faces,
                                                     const float* __restrict__ uvs,
                                                     const float* __restrict__ tex,
                                                     float* __restrict__ out) {
    __shared__ float4 sA[kF], sB[kF], sC[kF];  // 24 KB
    __shared__ float2 s_vtx[kF * 3];           // 12 KB
    __shared__ unsigned short s_of[kF];        // 1 KB
    __shared__ int s_wsum[8];
    __shared__ float s_bz[512];
    __shared__ int s_bi[512];
    __shared__ float s_lm[512];

    int tile = (int)blockIdx.x;
    int b = tile >> 8;
    int rem = tile & 255;
    int ty = rem >> 4, tx = rem & 15;
    int tid = (int)threadIdx.x;
    int lane = tid & 63;
    int wv = tid >> 6;

    // ---------- setup: thread tid processes face tid for batch b ----------
    {
        int f = tid;
        int i0 = faces[f * 3 + 0], i1 = faces[f * 3 + 1], i2 = faces[f * 3 + 2];
        const float* pb = pts + b * kP * 3;
        float x0 = pb[i0 * 3], y0 = pb[i0 * 3 + 1], z0 = pb[i0 * 3 + 2];
        float x1 = pb[i1 * 3], y1 = pb[i1 * 3 + 1], z1 = pb[i1 * 3 + 2];
        float x2 = pb[i2 * 3], y2 = pb[i2 * 3 + 1], z2 = pb[i2 * 3 + 2];
        float area = (x1 - x0) * (y2 - y0) - (y1 - y0) * (x2 - x0);
        bool front = area > 1e-8f;

        // prefill: empty slots yield L0=L1=L2=-1e30 (never inside) and
        // verts at 1e15 -> cull d2 ~ 1e30 (never admitted); NaN-free.
        sA[f] = make_float4(0.0f, 0.0f, -1e30f, 0.0f);
        sB[f] = make_float4(0.0f, -1e30f, 0.0f, 0.0f);
        sC[f] = make_float4(-1e30f, 0.0f, 0.0f, 0.0f);
        s_vtx[f * 3 + 0] = make_float2(1e15f, 1e15f);
        s_vtx[f * 3 + 1] = make_float2(1e15f, 1e15f);
        s_vtx[f * 3 + 2] = make_float2(1e15f, 1e15f);
        unsigned long long bal = __ballot(front);
        if (lane == 0) s_wsum[wv] = __popcll(bal);
        __syncthreads();  // wsum + prefill visible

        int base = 0;
#pragma unroll
        for (int w = 0; w < 8; ++w) base += (w < wv) ? s_wsum[w] : 0;
        int k = base + __popcll(bal & ((1ull << lane) - 1ull));  // compacted idx

        if (front) {
            int slot = ((k & 7) << 6) | (k >> 3);  // deal across waves
            float inv_a = 1.0f / area;
            float e0x = x2 - x1, e0y = y2 - y1;
            float e1x = x0 - x2, e1y = y0 - y2;
            float e2x = x1 - x0, e2y = y1 - y0;
            float l0 = fmaf(e0x, e0x, e0y * e0y);
            float l1 = fmaf(e1x, e1x, e1y * e1y);
            float l2 = fmaf(e2x, e2x, e2y * e2y);
            float s0 = rsqrtf(l0 + 1e-12f);
            float s1 = rsqrtf(l1 + 1e-12f);
            float s2 = rsqrtf(l2 + 1e-12f);
            float A0 = -e0y * s0, B0 = e0x * s0, C0 = (e0y * x1 - e0x * y1) * s0;
            float A1 = -e1y * s1, B1 = e1x * s1, C1 = (e1y * x2 - e1x * y2) * s1;
            float A2 = -e2y * s2, B2 = e2x * s2, C2 = (e2y * x0 - e2x * y0) * s2;
            float a0 = -e0y * inv_a, b0 = e0x * inv_a, c0 = (e0y * x1 - e0x * y1) * inv_a;
            float a1 = -e1y * inv_a, b1 = e1x * inv_a, c1 = (e1y * x2 - e1x * y2) * inv_a;
            float a2 = -e2y * inv_a, b2 = e2x * inv_a, c2 = (e2y * x0 - e2x * y0) * inv_a;
            sA[slot] = make_float4(A0, B0, C0, A1);
            sB[slot] = make_float4(B1, C1, A2, B2);
            sC[slot] = make_float4(C2,
                                   a0 * z0 + a1 * z1 + a2 * z2,
                                   b0 * z0 + b1 * z1 + b2 * z2,
                                   c0 * z0 + c1 * z1 + c2 * z2);
            s_vtx[slot * 3 + 0] = make_float2(x0, y0);
            s_vtx[slot * 3 + 1] = make_float2(x1, y1);
            s_vtx[slot * 3 + 2] = make_float2(x2, y2);
            s_of[slot] = (unsigned short)f;
        }
    }
    __syncthreads();

    // ---------- render ----------
    int pyi = ty * 8 + (lane >> 3);
    int pxi = tx * 8 + (lane & 7);
    float px = ((float)pxi + 0.5f) * (2.0f / 128.0f) - 1.0f;
    float py = 1.0f - ((float)pyi + 0.5f) * (2.0f / 128.0f);

    // ---- cull: lane l tests slot wv*64+l with EXACT dist-to-triangle at
    // tile center (admit iff inside || d2 <= (kCut + tile_radius)^2) ----
    float cx = (float)(tx * 8 + 4) * (2.0f / 128.0f) - 1.0f;
    float cy = 1.0f - (float)(ty * 8 + 4) * (2.0f / 128.0f);
    unsigned long long m;
    {
        int slt = (wv << 6) + lane;  // lane-contiguous -> conflict-free b128
        float4 a4 = sA[slt];
        float4 b4 = sB[slt];
        float4 c4 = sC[slt];
        float L0 = fmaf(a4.x, cx, fmaf(a4.y, cy, a4.z));
        float L1 = fmaf(a4.w, cx, fmaf(b4.x, cy, b4.y));
        float L2 = fmaf(b4.z, cx, fmaf(b4.w, cy, c4.x));
        float minc = fminf(fminf(L0, L1), L2);
        float2 v0 = s_vtx[slt * 3 + 0];
        float2 v1 = s_vtx[slt * 3 + 1];
        float2 v2 = s_vtx[slt * 3 + 2];
        float e0x = v2.x - v1.x, e0y = v2.y - v1.y;
        float e1x = v0.x - v2.x, e1y = v0.y - v2.y;
        float e2x = v1.x - v0.x, e2y = v1.y - v0.y;
        float p0x = cx - v0.x, p0y = cy - v0.y;
        float p1x = cx - v1.x, p1y = cy - v1.y;
        float p2x = cx - v2.x, p2y = cy - v2.y;
        float dot0 = fmaf(p1x, e0x, p1y * e0y), len0 = fmaf(e0x, e0x, e0y * e0y);
        float dot1 = fmaf(p2x, e1x, p2y * e1y), len1 = fmaf(e1x, e1x, e1y * e1y);
        float dot2 = fmaf(p0x, e2x, p0y * e2y), len2 = fmaf(e2x, e2x, e2y * e2y);
        float c0 = (dot0 >= 0.0f && dot0 <= len0) ? L0 * L0 : 1e30f;
        float c1 = (dot1 >= 0.0f && dot1 <= len1) ? L1 * L1 : 1e30f;
        float c2 = (dot2 >= 0.0f && dot2 <= len2) ? L2 * L2 : 1e30f;
        float dv0 = fmaf(p0x, p0x, p0y * p0y);
        float dv1 = fmaf(p1x, p1x, p1y * p1y);
        float dv2 = fmaf(p2x, p2x, p2y * p2y);
        float d2c = fminf(fminf(fminf(c0, c1), fminf(c2, dv0)), fminf(dv1, dv2));
        bool admit = (minc >= 0.0f) | (d2c <= kThr2);
        m = __ballot(admit);
    }

    float bestz = -1e9f;
    int besti = -1, icnt = 0;   // besti holds compacted index k (global order)
    float lm = 0.0f;

    while (m) {
        int l = (int)__builtin_ctzll(m);
        m &= (m - 1);
        int fs = (wv << 6) + l;         // LDS slot (wave-uniform)
        int k = (l << 3) | wv;          // compacted face index, ascending in l
        float4 h0 = sA[fs];
        float4 h1 = sB[fs];
        float4 h2 = sC[fs];
        float L0 = fmaf(h0.x, px, fmaf(h0.y, py, h0.z));
        float L1 = fmaf(h0.w, px, fmaf(h1.x, py, h1.y));
        float L2 = fmaf(h1.z, px, fmaf(h1.w, py, h2.x));
        float minL = fminf(fminf(L0, L1), L2);
        bool inside = minL >= 0.0f;
        float z = fmaf(h2.y, px, fmaf(h2.z, py, h2.w));
        if (inside && z > bestz) { bestz = z; besti = k; }
        icnt += inside ? 1 : 0;
        float db = fminf(fminf(fabsf(L0), fabsf(L1)), fabsf(L2));
        bool need = (!inside) & (db < kCut);
        if (__any(need)) {
            float2 v0 = s_vtx[fs * 3 + 0];
            float2 v1 = s_vtx[fs * 3 + 1];
            float2 v2 = s_vtx[fs * 3 + 2];
            float e0x = v2.x - v1.x, e0y = v2.y - v1.y;
            float e1x = v0.x - v2.x, e1y = v0.y - v2.y;
            float e2x = v1.x - v0.x, e2y = v1.y - v0.y;
            float p0x = px - v0.x, p0y = py - v0.y;
            float p1x = px - v1.x, p1y = py - v1.y;
            float p2x = px - v2.x, p2y = py - v2.y;
            float dot0 = fmaf(p1x, e0x, p1y * e0y), len0 = fmaf(e0x, e0x, e0y * e0y);
            float dot1 = fmaf(p2x, e1x, p2y * e1y), len1 = fmaf(e1x, e1x, e1y * e1y);
            float dot2 = fmaf(p0x, e2x, p0y * e2y), len2 = fmaf(e2x, e2x, e2y * e2y);
            float c0 = (dot0 >= 0.0f && dot0 <= len0) ? L0 * L0 : 1e30f;
            float c1 = (dot1 >= 0.0f && dot1 <= len1) ? L1 * L1 : 1e30f;
            float c2 = (dot2 >= 0.0f && dot2 <= len2) ? L2 * L2 : 1e30f;
            float dv0 = fmaf(p0x, p0x, p0y * p0y);
            float dv1 = fmaf(p1x, p1x, p1y * p1y);
            float dv2 = fmaf(p2x, p2x, p2y * p2y);
            float d2 = fminf(fminf(fminf(c0, c1), fminf(c2, dv0)), fminf(dv1, dv2));
            float p = __expf(-kDelta * d2);
            p = fminf(p, 1.0f - 1e-7f);
            float lp = __logf(1.0f - p);  // == log1p(-p): 1-p exact for p >= 0.5
            lm += need ? lp : 0.0f;
        }
    }
    lm = fmaf((float)icnt, kLogInside, lm);

    s_bz[tid] = bestz;
    s_bi[tid] = besti;
    s_lm[tid] = lm;
    __syncthreads();

    if (tid < 64) {
        float bz = s_bz[tid];
        int bi = s_bi[tid];
        float L = s_lm[tid];
#pragma unroll
        for (int w = 1; w < 8; ++w) {
            float z2 = s_bz[w * 64 + tid];
            int ii = s_bi[w * 64 + tid];
            L += s_lm[w * 64 + tid];
            // first-max: lowest compacted index (== earliest original face) wins ties
            if (z2 > bz || (z2 == bz && ii >= 0 && (unsigned)ii < (unsigned)bi)) {
                bz = z2; bi = ii;
            }
        }
        float improb = 1.0f - expf(L);
        float u = 0.0f, v = 0.0f, mk = 0.0f;
        if (bi >= 0) {
            int slot = ((bi & 7) << 6) | (bi >> 3);
            float2 v0 = s_vtx[slot * 3 + 0];
            float2 v1 = s_vtx[slot * 3 + 1];
            float2 v2 = s_vtx[slot * 3 + 2];
            float area = (v1.x - v0.x) * (v2.y - v0.y) - (v1.y - v0.y) * (v2.x - v0.x);
            float inv_a = 1.0f / area;
            // exact reference formulation
            float w0 = ((v2.x - v1.x) * (py - v1.y) - (v2.y - v1.y) * (px - v1.x)) * inv_a;
            float w1 = ((v0.x - v2.x) * (py - v2.y) - (v0.y - v2.y) * (px - v2.x)) * inv_a;
            float w2 = ((v1.x - v0.x) * (py - v0.y) - (v1.y - v0.y) * (px - v0.x)) * inv_a;
            int of = (int)s_of[slot];
            int j0 = faces[of * 3], j1 = faces[of * 3 + 1], j2 = faces[of * 3 + 2];
            const float* ub = uvs + b * kP * 2;
            u = w0 * ub[j0 * 2] + w1 * ub[j1 * 2] + w2 * ub[j2 * 2];
            v = w0 * ub[j0 * 2 + 1] + w1 * ub[j1 * 2 + 1] + w2 * ub[j2 * 2 + 1];
            mk = w0 + w1 + w2;
        }
        float uc = fminf(fmaxf(u, 0.0f), 1.0f);
        float vc = fminf(fmaxf(v, 0.0f), 1.0f);
        float fx = uc * (float)(kTW - 1);
        float fy = (1.0f - vc) * (float)(kTH - 1);
        int xi0 = (int)floorf(fx), yi0 = (int)floorf(fy);
        int xi1 = min(xi0 + 1, kTW - 1), yi1 = min(yi0 + 1, kTH - 1);
        float wx = fx - (float)xi0, wy = fy - (float)yi0;
        float w00 = (1.0f - wx) * (1.0f - wy);
        float w01 = wx * (1.0f - wy);
        float w10 = (1.0f - wx) * wy;
        float w11 = wx * wy;
        int o00 = yi0 * kTW + xi0, o01 = yi0 * kTW + xi1;
        int o10 = yi1 * kTW + xi0, o11 = yi1 * kTW + xi1;
        const float* tb = tex + (size_t)b * 3 * kTH * kTW;
        float cols[3];
#pragma unroll
        for (int c = 0; c < 3; ++c) {
            const float* tc = tb + c * kTH * kTW;
            cols[c] = (tc[o00] * w00 + tc[o01] * w01 + tc[o10] * w10 + tc[o11] * w11) * mk;
        }
        int pix = (b * kH + pyi) * kW + pxi;
        out[pix * 3 + 0] = cols[0];
        out[pix * 3 + 1] = cols[1];
        out[pix * 3 + 2] = cols[2];
        out[kB * kH * kW * 3 + pix] = improb;
    }
}

extern "C" void kernel_launch(void* const* d_in, const int* in_sizes, int n_in,
                              void* d_out, int out_size, void* d_ws, size_t ws_size,
                              hipStream_t stream) {
    const float* pts = (const float*)d_in[0];
    const int* faces = (const int*)d_in[1];
    const float* uvs = (const float*)d_in[2];
    const float* tex = (const float*)d_in[3];
    float* out = (float*)d_out;
    render_all<<<kB * 256, 512, 0, stream>>>(pts, faces, uvs, tex, out);
}